// Round 3
// baseline (49.331 us; speedup 1.0000x reference)
//
#include <hip/hip_runtime.h>

// Project each 2-D fp32 point onto the unit L2 ball: y = x / max(1, ||x||2).
// B = 16777216 points -> 33554432 floats -> 8388608 vec4 (2 points per vec4).
// Memory-bound streaming op: non-temporal load/store (native clang vector type,
// HIP_vector_type structs are rejected by the builtin) to keep L2/L3 free for
// the read stream; grid-stride with 4096 blocks for memory-level parallelism.

typedef float vfloat4 __attribute__((ext_vector_type(4)));

__global__ void __launch_bounds__(256) proj_l2ball_kernel(
    const vfloat4* __restrict__ in, vfloat4* __restrict__ out, int n4) {
    int idx = blockIdx.x * blockDim.x + threadIdx.x;
    int stride = gridDim.x * blockDim.x;
    for (int i = idx; i < n4; i += stride) {
        vfloat4 v = __builtin_nontemporal_load(&in[i]);
        // point 0 = (v.x, v.y), point 1 = (v.z, v.w)
        float n0 = sqrtf(v.x * v.x + v.y * v.y);
        float n1 = sqrtf(v.z * v.z + v.w * v.w);
        float s0 = n0 > 1.0f ? 1.0f / n0 : 1.0f;
        float s1 = n1 > 1.0f ? 1.0f / n1 : 1.0f;
        vfloat4 r;
        r.x = v.x * s0;
        r.y = v.y * s0;
        r.z = v.z * s1;
        r.w = v.w * s1;
        __builtin_nontemporal_store(r, &out[i]);
    }
}

extern "C" void kernel_launch(void* const* d_in, const int* in_sizes, int n_in,
                              void* d_out, int out_size, void* d_ws, size_t ws_size,
                              hipStream_t stream) {
    const vfloat4* in = (const vfloat4*)d_in[0];
    vfloat4* out = (vfloat4*)d_out;
    int n_floats = in_sizes[0];          // 33554432
    int n4 = n_floats / 4;               // 8388608
    int block = 256;
    int grid = 4096;                     // grid-stride: ~8 iters/thread
    proj_l2ball_kernel<<<grid, block, 0, stream>>>(in, out, n4);
}

// Round 4
// 45.840 us; speedup vs baseline: 1.0762x; 1.0762x over previous
//
#include <hip/hip_runtime.h>

// Project each 2-D fp32 point onto the unit L2 ball: y = x / max(1, ||x||2).
// B = 16777216 points -> 33554432 floats -> 8388608 vec4 (2 points per vec4).
// Memory-bound streaming op. Loads are NORMAL (cached): L3 serves ~half the
// read stream (round-1 FETCH_SIZE evidence); NT loads lost that (+7%, round 3).
// Store is non-temporal: output is write-once, keep it from evicting input.

typedef float vfloat4 __attribute__((ext_vector_type(4)));

__global__ void __launch_bounds__(256) proj_l2ball_kernel(
    const vfloat4* __restrict__ in, vfloat4* __restrict__ out, int n4) {
    int idx = blockIdx.x * blockDim.x + threadIdx.x;
    int stride = gridDim.x * blockDim.x;
    for (int i = idx; i < n4; i += stride) {
        vfloat4 v = in[i];
        // point 0 = (v.x, v.y), point 1 = (v.z, v.w)
        float n0 = sqrtf(v.x * v.x + v.y * v.y);
        float n1 = sqrtf(v.z * v.z + v.w * v.w);
        float s0 = n0 > 1.0f ? 1.0f / n0 : 1.0f;
        float s1 = n1 > 1.0f ? 1.0f / n1 : 1.0f;
        vfloat4 r;
        r.x = v.x * s0;
        r.y = v.y * s0;
        r.z = v.z * s1;
        r.w = v.w * s1;
        __builtin_nontemporal_store(r, &out[i]);
    }
}

extern "C" void kernel_launch(void* const* d_in, const int* in_sizes, int n_in,
                              void* d_out, int out_size, void* d_ws, size_t ws_size,
                              hipStream_t stream) {
    const vfloat4* in = (const vfloat4*)d_in[0];
    vfloat4* out = (vfloat4*)d_out;
    int n_floats = in_sizes[0];          // 33554432
    int n4 = n_floats / 4;               // 8388608
    int block = 256;
    int grid = 2048;                     // grid-stride: ~16 iters/thread (round-1 config)
    proj_l2ball_kernel<<<grid, block, 0, stream>>>(in, out, n4);
}